// Round 3
// baseline (16.774 us; speedup 1.0000x reference)
//
#include <hip/hip_runtime.h>
#include <math.h>

#define NQ    12
#define DIM   4096
#define BATCH 512

// float2-granular padded LDS index: +2 float2 per 16 keeps b128 writes
// 16B-aligned and every exchange pattern at minimum bank aliasing.
#define PAD2(i) ((i) + 2 * ((i) >> 4))

// One butterfly level over the 8 register-resident float2 amplitudes.
// GA = (g00r,g00i,g01r,g01i), GB = (g10r,g10i,g11r,g11i). J in {0,1,2}.
#define LEVEL(GA, GB, J) do {                                               \
    _Pragma("unroll")                                                       \
    for (int p = 0; p < 4; ++p) {                                           \
        const int r0 = ((p >> (J)) << ((J) + 1)) | (p & ((1 << (J)) - 1));  \
        const int r1 = r0 | (1 << (J));                                     \
        const float ar = x[r0].x, ai = x[r0].y;                             \
        const float br = x[r1].x, bi = x[r1].y;                             \
        x[r0].x = GA.x * ar - GA.y * ai + GA.z * br - GA.w * bi;            \
        x[r0].y = GA.x * ai + GA.y * ar + GA.z * bi + GA.w * br;            \
        x[r1].x = GB.x * ar - GB.y * ai + GB.z * br - GB.w * bi;            \
        x[r1].y = GB.x * ai + GB.y * ar + GB.z * bi + GB.w * br;            \
    }                                                                       \
} while (0)

// Three levels; qa acts on local bit 0, qb on bit 1, qc on bit 2.
#define STAGE(qa, qb, qc) do {                                              \
    const float4 A0 = ((const float4*)g[qa])[0], A1 = ((const float4*)g[qa])[1]; \
    const float4 B0 = ((const float4*)g[qb])[0], B1 = ((const float4*)g[qb])[1]; \
    const float4 C0 = ((const float4*)g[qc])[0], C1 = ((const float4*)g[qc])[1]; \
    LEVEL(A0, A1, 0);                                                       \
    LEVEL(B0, B1, 1);                                                       \
    LEVEL(C0, C1, 2);                                                       \
} while (0)

__global__ __launch_bounds__(512, 4) void u3_apply_kernel(
    const float* __restrict__ thetas,   // [12,3]
    const float* __restrict__ sre,      // [512,4096]
    const float* __restrict__ sim_,     // [512,4096]
    float*       __restrict__ out)      // [512,4096,2]
{
    __shared__ __align__(16) float2 L[4608];    // PAD2(4095)+1 = 4606
    __shared__ __align__(16) float  g[NQ][8];

    const int b = blockIdx.x;
    const int t = threadIdx.x;

    // ---- gates (threads 0..11); gate q acts on state bit (11-q) ----
    if (t < NQ) {
        float th = thetas[t * 3 + 0];
        float ph = thetas[t * 3 + 1];
        float la = thetas[t * 3 + 2];
        float c, s, cl, sl, cp, sp;
        __sincosf(th * 0.5f, &s, &c);
        __sincosf(la, &sl, &cl);
        __sincosf(ph, &sp, &cp);
        g[t][0] = c;        g[t][1] = 0.0f;
        g[t][2] = -cl * s;  g[t][3] = -sl * s;
        g[t][4] = cp * s;   g[t][5] = sp * s;
        g[t][6] = (cp * cl - sp * sl) * c;
        g[t][7] = (sp * cl + cp * sl) * c;
    }

    // ---- global -> registers: thread t owns idx = 8t + r (bits 2:0 local)
    float2 x[8];
    {
        const float4* pre = (const float4*)(sre  + (size_t)b * DIM) + 2 * t;
        const float4* pim = (const float4*)(sim_ + (size_t)b * DIM) + 2 * t;
        float4 vr0 = pre[0], vr1 = pre[1];
        float4 vi0 = pim[0], vi1 = pim[1];
        x[0] = make_float2(vr0.x, vi0.x); x[1] = make_float2(vr0.y, vi0.y);
        x[2] = make_float2(vr0.z, vi0.z); x[3] = make_float2(vr0.w, vi0.w);
        x[4] = make_float2(vr1.x, vi1.x); x[5] = make_float2(vr1.y, vi1.y);
        x[6] = make_float2(vr1.z, vi1.z); x[7] = make_float2(vr1.w, vi1.w);
    }

    __syncthreads();            // gates visible (overlaps global-load latency)

    // ---- stage A: bits 0,1,2 -> gates 11,10,9 ----
    STAGE(11, 10, 9);

    // exchange 1: contiguous b128 write, read bits 5:3 local
#pragma unroll
    for (int k = 0; k < 4; ++k) {
        *(float4*)&L[PAD2(8 * t + 2 * k)] =
            make_float4(x[2 * k].x, x[2 * k].y, x[2 * k + 1].x, x[2 * k + 1].y);
    }
    __syncthreads();
    {
        const int base = ((t >> 3) << 6) | (t & 7);
#pragma unroll
        for (int r = 0; r < 8; ++r) x[r] = L[PAD2(base + (r << 3))];
    }

    // ---- stage B: bits 3,4,5 -> gates 8,7,6 ----
    STAGE(8, 7, 6);

    // exchange 2: write back to the SAME slots just read (no WAR hazard),
    // then read bits 8:6 local
    {
        const int base = ((t >> 3) << 6) | (t & 7);
#pragma unroll
        for (int r = 0; r < 8; ++r) L[PAD2(base + (r << 3))] = x[r];
    }
    __syncthreads();
    {
        const int base = ((t >> 6) << 9) | (t & 63);
#pragma unroll
        for (int r = 0; r < 8; ++r) x[r] = L[PAD2(base + (r << 6))];
    }

    // ---- stage C: bits 6,7,8 -> gates 5,4,3 ----
    STAGE(5, 4, 3);

    // exchange 3: write back same slots, read bits 11:9 local
    {
        const int base = ((t >> 6) << 9) | (t & 63);
#pragma unroll
        for (int r = 0; r < 8; ++r) L[PAD2(base + (r << 6))] = x[r];
    }
    __syncthreads();
#pragma unroll
    for (int r = 0; r < 8; ++r) x[r] = L[PAD2((r << 9) | t)];

    // ---- stage D: bits 9,10,11 -> gates 2,1,0 ----
    STAGE(2, 1, 0);

    // ---- store: idx = (r<<9)|t -> consecutive float2 across lanes ----
    {
        float2* o2 = (float2*)out + (size_t)b * DIM;
#pragma unroll
        for (int r = 0; r < 8; ++r) o2[(r << 9) | t] = x[r];
    }
}

extern "C" void kernel_launch(void* const* d_in, const int* in_sizes, int n_in,
                              void* d_out, int out_size, void* d_ws, size_t ws_size,
                              hipStream_t stream) {
    const float* thetas = (const float*)d_in[0];
    const float* sre    = (const float*)d_in[1];
    const float* sim_   = (const float*)d_in[2];
    float* out = (float*)d_out;

    u3_apply_kernel<<<BATCH, 512, 0, stream>>>(thetas, sre, sim_, out);
}

// Round 5
// 16.163 us; speedup vs baseline: 1.0378x; 1.0378x over previous
//
#include <hip/hip_runtime.h>
#include <math.h>

#define NQ    12
#define DIM   4096
#define BATCH 512

typedef float nt_f2 __attribute__((ext_vector_type(2)));

// float2-granular padded LDS index: +2 float2 per 16.
// Verified: exchange-1 b128 writes = 8 cy (min), exchange-1 b64 reads and
// exchange-2 b64 write/read = 4 cy (min). All accesses naturally aligned.
#define PAD2(i) ((i) + 2 * ((i) >> 4))

// One butterfly level over the 16 register-resident float2 amplitudes.
// GA = (g00r,g00i,g01r,g01i), GB = (g10r,g10i,g11r,g11i). J in {0..3}.
#define LEVEL(q, J) do {                                                    \
    const float4 GA = *(const float4*)&g[q][0];                             \
    const float4 GB = *(const float4*)&g[q][4];                             \
    _Pragma("unroll")                                                       \
    for (int p = 0; p < 8; ++p) {                                           \
        const int r0 = ((p >> (J)) << ((J) + 1)) | (p & ((1 << (J)) - 1));  \
        const int r1 = r0 | (1 << (J));                                     \
        const float ar = x[r0].x, ai = x[r0].y;                             \
        const float br = x[r1].x, bi = x[r1].y;                             \
        x[r0].x = GA.x * ar - GA.y * ai + GA.z * br - GA.w * bi;            \
        x[r0].y = GA.x * ai + GA.y * ar + GA.z * bi + GA.w * br;            \
        x[r1].x = GB.x * ar - GB.y * ai + GB.z * br - GB.w * bi;            \
        x[r1].y = GB.x * ai + GB.y * ar + GB.z * bi + GB.w * br;            \
    }                                                                       \
} while (0)

__global__ __launch_bounds__(256) void u3_apply_kernel(
    const float* __restrict__ thetas,   // [12,3]
    const float* __restrict__ sre,      // [512,4096]
    const float* __restrict__ sim_,     // [512,4096]
    float*       __restrict__ out)      // [512,4096,2]
{
    __shared__ __align__(16) float2 L[4608];     // PAD2(4095)+1 = 4606
    __shared__ __align__(16) float  g[NQ][8];

    const int b = blockIdx.x;
    const int t = threadIdx.x;

    // ---- issue global loads first (latency hides under gate sincos) ----
    const float4* pre = (const float4*)(sre  + (size_t)b * DIM) + 4 * t;
    const float4* pim = (const float4*)(sim_ + (size_t)b * DIM) + 4 * t;
    float4 vr0 = pre[0], vr1 = pre[1], vr2 = pre[2], vr3 = pre[3];
    float4 vi0 = pim[0], vi1 = pim[1], vi2 = pim[2], vi3 = pim[3];

    // ---- gates (threads 0..11); gate q acts on state bit (11-q) ----
    if (t < NQ) {
        float th = thetas[t * 3 + 0];
        float ph = thetas[t * 3 + 1];
        float la = thetas[t * 3 + 2];
        float c, s, cl, sl, cp, sp;
        __sincosf(th * 0.5f, &s, &c);
        __sincosf(la, &sl, &cl);
        __sincosf(ph, &sp, &cp);
        g[t][0] = c;        g[t][1] = 0.0f;
        g[t][2] = -cl * s;  g[t][3] = -sl * s;
        g[t][4] = cp * s;   g[t][5] = sp * s;
        g[t][6] = (cp * cl - sp * sl) * c;
        g[t][7] = (sp * cl + cp * sl) * c;
    }
    __syncthreads();    // #1: gates visible

    // ---- unpack: thread t owns idx = (t<<4)|r, r = bits 3:0 ----
    float2 x[16];
    x[ 0] = make_float2(vr0.x, vi0.x); x[ 1] = make_float2(vr0.y, vi0.y);
    x[ 2] = make_float2(vr0.z, vi0.z); x[ 3] = make_float2(vr0.w, vi0.w);
    x[ 4] = make_float2(vr1.x, vi1.x); x[ 5] = make_float2(vr1.y, vi1.y);
    x[ 6] = make_float2(vr1.z, vi1.z); x[ 7] = make_float2(vr1.w, vi1.w);
    x[ 8] = make_float2(vr2.x, vi2.x); x[ 9] = make_float2(vr2.y, vi2.y);
    x[10] = make_float2(vr2.z, vi2.z); x[11] = make_float2(vr2.w, vi2.w);
    x[12] = make_float2(vr3.x, vi3.x); x[13] = make_float2(vr3.y, vi3.y);
    x[14] = make_float2(vr3.z, vi3.z); x[15] = make_float2(vr3.w, vi3.w);

    // ---- stage A: state bits 0..3 -> gates 11,10,9,8 ----
    LEVEL(11, 0); LEVEL(10, 1); LEVEL(9, 2); LEVEL(8, 3);

    // ---- exchange 1: b128 contiguous write; read -> reg = bits 7:4 ----
#pragma unroll
    for (int k = 0; k < 8; ++k) {
        *(float4*)&L[PAD2((t << 4) | (2 * k))] =
            make_float4(x[2 * k].x, x[2 * k].y, x[2 * k + 1].x, x[2 * k + 1].y);
    }
    __syncthreads();    // #2
    {
        const int base = ((t & 0xF0) << 4) | (t & 15);
#pragma unroll
        for (int r = 0; r < 16; ++r) x[r] = L[PAD2(base | (r << 4))];
    }

    // ---- stage B: state bits 4..7 -> gates 7,6,5,4 ----
    LEVEL(7, 0); LEVEL(6, 1); LEVEL(5, 2); LEVEL(4, 3);

    // ---- exchange 2: write back to the SAME slots just read (no WAR),
    //      then read -> reg = bits 11:8 ----
    {
        const int base = ((t & 0xF0) << 4) | (t & 15);
#pragma unroll
        for (int r = 0; r < 16; ++r) L[PAD2(base | (r << 4))] = x[r];
    }
    __syncthreads();    // #3
#pragma unroll
    for (int r = 0; r < 16; ++r) x[r] = L[PAD2((r << 8) | t)];

    // ---- stage C: state bits 8..11 -> gates 3,2,1,0 ----
    LEVEL(3, 0); LEVEL(2, 1); LEVEL(1, 2); LEVEL(0, 3);

    // ---- store: idx = (r<<8)|t, consecutive float2 across lanes ----
    {
        float2* o2 = (float2*)out + (size_t)b * DIM;
#pragma unroll
        for (int r = 0; r < 16; ++r) {
            nt_f2 v; v.x = x[r].x; v.y = x[r].y;
            __builtin_nontemporal_store(v, (nt_f2*)&o2[(r << 8) | t]);
        }
    }
}

extern "C" void kernel_launch(void* const* d_in, const int* in_sizes, int n_in,
                              void* d_out, int out_size, void* d_ws, size_t ws_size,
                              hipStream_t stream) {
    const float* thetas = (const float*)d_in[0];
    const float* sre    = (const float*)d_in[1];
    const float* sim_   = (const float*)d_in[2];
    float* out = (float*)d_out;

    u3_apply_kernel<<<BATCH, 256, 0, stream>>>(thetas, sre, sim_, out);
}